// Round 13
// baseline (26.091 us; speedup 1.0000x reference)
//
#include <hip/hip_runtime.h>

// Problem constants (B=1)
#define H 8
#define S 4096
#define D 64          // D1 == D2 == 64
#define C 64          // chunk length
#define NC (S / C)    // 64 chunks per head
#define DD (D * D)
#define PITCH 72      // bf16 LDS row pitch (144B, 16B-aligned, 4-bank rotation)

typedef short bf16x8 __attribute__((ext_vector_type(8)));
typedef float f32x4 __attribute__((ext_vector_type(4)));
typedef unsigned uint4v __attribute__((ext_vector_type(4)));

struct alignas(16) F4 { float v[4]; };

__device__ inline unsigned short rne_bf16(float x) {
  unsigned u = __builtin_bit_cast(unsigned, x);
  unsigned r = u + 0x7fffu + ((u >> 16) & 1u);
  return (unsigned short)(r >> 16);
}
__device__ inline float bf16_to_f(unsigned hw) {
  return __builtin_bit_cast(float, hw << 16);
}

// ---------------------------------------------------------------------------
// Kernel 1 (512 thr, 8 waves): per-chunk state via MFMA + v^T export:
//   wsKV[h][ch][c][a] = bf16( sum_i v[i][c] * k_bar[i][a] )
//   wsVT[h][ch][c][i] = bf16( v[i][c] )          (transposed v, for k3)
// Also streams q through L3 (prefetch for k3).
// ---------------------------------------------------------------------------
__global__ __launch_bounds__(512, 4) void k_chunk_sums(
    const float* __restrict__ k, const float* __restrict__ v,
    const float* __restrict__ q, const float* __restrict__ coef_k,
    unsigned short* __restrict__ wsKV, unsigned short* __restrict__ wsVT) {
  const int ch = blockIdx.x, h = blockIdx.y, t = threadIdx.x;
  __shared__ alignas(16) short kT[C * PITCH];   // k_bar^T [a][i]
  __shared__ alignas(16) short vT[C * PITCH];   // v^T     [c][i]

  const float* kp = k + (size_t)(h * S + ch * C) * D;
  const float* vp = v + (size_t)(h * S + ch * C) * D;
  const float* qp = q + (size_t)(h * S + ch * C) * D;
  const float* ck = coef_k + h * S + ch * C;

  // q L3-prefetch: 32B per thread covers the whole 16KB chunk of q
  {
    F4 q0 = *reinterpret_cast<const F4*>(qp + 8 * t);
    F4 q1 = *reinterpret_cast<const F4*>(qp + 8 * t + 4);
    float s = (q0.v[0] + q0.v[3]) + (q1.v[0] + q1.v[3]);
    asm volatile("" :: "v"(s));   // keep loads live, discard value
  }

  // staging: col = t&63; grp = t>>6: grp<4 -> kT (i0=16*grp), else vT
  {
    const int col = t & 63, grp = t >> 6;
    const bool isK = grp < 4;
    const int i0 = (grp & 3) * 16;
    const float* src = isK ? kp : vp;
    short* dstT = isK ? kT : vT;
    unsigned pr[8];
#pragma unroll
    for (int u2 = 0; u2 < 8; ++u2) {
      const int ia = i0 + 2 * u2, ib = ia + 1;
      float x0 = src[ia * D + col];
      float x1 = src[ib * D + col];
      if (isK) { x0 *= ck[ia]; x1 *= ck[ib]; }
      pr[u2] = (unsigned)rne_bf16(x0) | ((unsigned)rne_bf16(x1) << 16);
    }
    uint4v w0 = {pr[0], pr[1], pr[2], pr[3]};
    uint4v w1 = {pr[4], pr[5], pr[6], pr[7]};
    *reinterpret_cast<uint4v*>(&dstT[col * PITCH + i0]) = w0;
    *reinterpret_cast<uint4v*>(&dstT[col * PITCH + i0 + 8]) = w1;
    if (!isK) {  // export v^T tile straight from registers
      unsigned short* vdst = wsVT + (size_t)(h * NC + ch) * DD + col * D + i0;
      *reinterpret_cast<uint4v*>(vdst) = w0;
      *reinterpret_cast<uint4v*>(vdst + 8) = w1;
    }
  }
  __syncthreads();

  // MFMA: wave w -> row-tile m = w>>1 (c), col-tiles n0..n0+1 (a)
  const int lane = t & 63, w = t >> 6;
  const int arow = lane & 15, kg = lane >> 4;
  const int m = w >> 1, n0 = 2 * (w & 1);
  const int abase = (16 * m + arow) * PITCH + 8 * kg;
  bf16x8 a0 = *reinterpret_cast<const bf16x8*>(&vT[abase]);
  bf16x8 a1 = *reinterpret_cast<const bf16x8*>(&vT[abase + 32]);
  unsigned short* dst = wsKV + (size_t)(h * NC + ch) * DD;
#pragma unroll
  for (int nn = 0; nn < 2; ++nn) {
    const int n = n0 + nn;
    const int bb = (16 * n + arow) * PITCH + 8 * kg;
    bf16x8 b0 = *reinterpret_cast<const bf16x8*>(&kT[bb]);
    bf16x8 b1 = *reinterpret_cast<const bf16x8*>(&kT[bb + 32]);
    f32x4 z = {0.f, 0.f, 0.f, 0.f};
    z = __builtin_amdgcn_mfma_f32_16x16x32_bf16(a0, b0, z, 0, 0, 0);
    z = __builtin_amdgcn_mfma_f32_16x16x32_bf16(a1, b1, z, 0, 0, 0);
#pragma unroll
    for (int r = 0; r < 4; ++r)
      dst[(16 * m + 4 * kg + r) * D + 16 * n + arow] = rne_bf16(z[r]);
  }
}

// ---------------------------------------------------------------------------
// Kernel 2: exclusive prefix scan across chunks (per head), bf16 in/out,
// f32 running sum, 32-deep load batching.
// ---------------------------------------------------------------------------
__global__ __launch_bounds__(64) void k_scan(unsigned* __restrict__ wsKV) {
  const int seg = blockIdx.x, h = blockIdx.y, t = threadIdx.x;
  const int e0 = seg * 64 + t;               // dword index within 2048-dword matrix
  float run0 = 0.f, run1 = 0.f;
  for (int base = 0; base < NC; base += 32) {
    unsigned x[32];
#pragma unroll
    for (int u = 0; u < 32; ++u)
      x[u] = wsKV[(size_t)(h * NC + base + u) * 2048 + e0];
#pragma unroll
    for (int u = 0; u < 32; ++u) {
      wsKV[(size_t)(h * NC + base + u) * 2048 + e0] =
          (unsigned)rne_bf16(run0) | ((unsigned)rne_bf16(run1) << 16);
      run0 += bf16_to_f(x[u] & 0xffffu);
      run1 += bf16_to_f(x[u] >> 16);
    }
  }
}

// ---------------------------------------------------------------------------
// Kernel 3 (512 thr, 8 waves): per-chunk output via MFMA.
//   A = tril(q_bar K_bar^T);  O = q_bar*S0 + A*V;  rmsnorm(O).
// S0 and v^T fragments hoisted from global at entry (L2/L3-hot);
// no vT gather, no vT/S0 LDS. qS0 MFMAs fill the Ab-barrier wait.
// ---------------------------------------------------------------------------
__global__ __launch_bounds__(512, 4) void k_chunk_out(
    const float* __restrict__ q, const float* __restrict__ k,
    const float* __restrict__ coef_q, const float* __restrict__ coef_k,
    const float* __restrict__ mask_normer,
    const unsigned short* __restrict__ wsKV,
    const unsigned short* __restrict__ wsVT, float* __restrict__ out) {
  const int ch = blockIdx.x, h = blockIdx.y, t = threadIdx.x;
  __shared__ alignas(16) short qb[C * PITCH];    // q_bar  [i][a]
  __shared__ alignas(16) short kbs[C * PITCH];   // k_bar  [j][a]
  __shared__ alignas(16) short Ab[C * PITCH];    // A      [i][j]
  __shared__ float ssp[C][2];                    // rms partials per row

  const size_t base = (size_t)(h * S + ch * C) * D;
  const float* qp = q + base;
  const float* kp = k + base;
  const float* cq = coef_q + h * S + ch * C;
  const float* ck = coef_k + h * S + ch * C;
  const float* mn = mask_normer + h * S + ch * C;

  const int lane = t & 63, w = t >> 6;
  const int arow = lane & 15, kg = lane >> 4;
  const int m = w >> 1, n0 = 2 * (w & 1);

  // ---- hoisted global fragment loads (S0, v^T), issue FIRST ----
  const unsigned short* s0p = wsKV + (size_t)(h * NC + ch) * DD;
  const unsigned short* vtp = wsVT + (size_t)(h * NC + ch) * DD;
  bf16x8 s0f[2][2], vf[2][2];
#pragma unroll
  for (int nn = 0; nn < 2; ++nn) {
    const int gb = (16 * (n0 + nn) + arow) * D + 8 * kg;
    s0f[nn][0] = *reinterpret_cast<const bf16x8*>(s0p + gb);
    s0f[nn][1] = *reinterpret_cast<const bf16x8*>(s0p + gb + 32);
    vf[nn][0]  = *reinterpret_cast<const bf16x8*>(vtp + gb);
    vf[nn][1]  = *reinterpret_cast<const bf16x8*>(vtp + gb + 32);
  }

  // ---- staging rows: thread t -> row i = t>>3, 8 cols c0 = (t&7)*8 ----
  {
    const int i = t >> 3, c0 = (t & 7) * 8;
    const float sq = cq[i] / mn[i];
    const float sk = ck[i];
    bf16x8 wq, wk;
#pragma unroll
    for (int u0 = 0; u0 < 8; u0 += 4) {
      F4 qv = *reinterpret_cast<const F4*>(qp + i * D + c0 + u0);
      F4 kv = *reinterpret_cast<const F4*>(kp + i * D + c0 + u0);
#pragma unroll
      for (int u = 0; u < 4; ++u) {
        wq[u0 + u] = (short)rne_bf16(qv.v[u] * sq);
        wk[u0 + u] = (short)rne_bf16(kv.v[u] * sk);
      }
    }
    *reinterpret_cast<bf16x8*>(&qb[i * PITCH + c0]) = wq;
    *reinterpret_cast<bf16x8*>(&kbs[i * PITCH + c0]) = wk;
  }
  __syncthreads();

  const int rbase = (16 * m + arow) * PITCH + 8 * kg;
  bf16x8 qa0 = *reinterpret_cast<const bf16x8*>(&qb[rbase]);
  bf16x8 qa1 = *reinterpret_cast<const bf16x8*>(&qb[rbase + 32]);

  // ---- A-stage: wave computes rows 16m..16m+15, cols 16n0..16n0+31 ----
#pragma unroll
  for (int nn = 0; nn < 2; ++nn) {
    const int n = n0 + nn;
    const int bb = (16 * n + arow) * PITCH + 8 * kg;
    bf16x8 b0 = *reinterpret_cast<const bf16x8*>(&kbs[bb]);
    bf16x8 b1 = *reinterpret_cast<const bf16x8*>(&kbs[bb + 32]);
    f32x4 z = {0.f, 0.f, 0.f, 0.f};
    z = __builtin_amdgcn_mfma_f32_16x16x32_bf16(qa0, b0, z, 0, 0, 0);
    z = __builtin_amdgcn_mfma_f32_16x16x32_bf16(qa1, b1, z, 0, 0, 0);
#pragma unroll
    for (int r = 0; r < 4; ++r) {
      int i = 16 * m + 4 * kg + r;
      int j = 16 * n + arow;
      float x = (j <= i) ? z[r] : 0.f;
      Ab[i * PITCH + j] = (short)rne_bf16(x);
    }
  }

  // ---- qS0 MFMAs (independent of Ab) fill the barrier wait ----
  f32x4 accO[2];
#pragma unroll
  for (int nn = 0; nn < 2; ++nn) {
    f32x4 z = {0.f, 0.f, 0.f, 0.f};
    z = __builtin_amdgcn_mfma_f32_16x16x32_bf16(qa0, s0f[nn][0], z, 0, 0, 0);
    z = __builtin_amdgcn_mfma_f32_16x16x32_bf16(qa1, s0f[nn][1], z, 0, 0, 0);
    accO[nn] = z;
  }
  __syncthreads();   // Ab complete

  // ---- AV accumulate (A-frags from LDS, v-frags hoisted) ----
  bf16x8 aa0 = *reinterpret_cast<const bf16x8*>(&Ab[rbase]);
  bf16x8 aa1 = *reinterpret_cast<const bf16x8*>(&Ab[rbase + 32]);
#pragma unroll
  for (int nn = 0; nn < 2; ++nn) {
    accO[nn] = __builtin_amdgcn_mfma_f32_16x16x32_bf16(aa0, vf[nn][0], accO[nn], 0, 0, 0);
    accO[nn] = __builtin_amdgcn_mfma_f32_16x16x32_bf16(aa1, vf[nn][1], accO[nn], 0, 0, 0);
  }

  // ---- rms partial: reduce over this wave's 32 cols, exchange halves ----
#pragma unroll
  for (int r = 0; r < 4; ++r) {
    float ss = accO[0][r] * accO[0][r] + accO[1][r] * accO[1][r];
#pragma unroll
    for (int off = 1; off < 16; off <<= 1) ss += __shfl_xor(ss, off);
    if (arow == 0) ssp[16 * m + 4 * kg + r][w & 1] = ss;
  }
  __syncthreads();

  // ---- epilogue: scale + store ----
  float* op = out + base;
#pragma unroll
  for (int r = 0; r < 4; ++r) {
    const int i = 16 * m + 4 * kg + r;
    const float tot = ssp[i][0] + ssp[i][1];
    const float sc = rsqrtf(tot * (1.0f / D) + 1e-6f);
#pragma unroll
    for (int nn = 0; nn < 2; ++nn)
      op[(size_t)i * D + 16 * (n0 + nn) + arow] = accO[nn][r] * sc;
  }
}

// ---------------------------------------------------------------------------
extern "C" void kernel_launch(void* const* d_in, const int* in_sizes, int n_in,
                              void* d_out, int out_size, void* d_ws, size_t ws_size,
                              hipStream_t stream) {
  (void)in_sizes; (void)n_in; (void)out_size; (void)ws_size;
  const float* q  = (const float*)d_in[0];
  const float* k  = (const float*)d_in[1];
  const float* v  = (const float*)d_in[2];
  const float* cq = (const float*)d_in[3];
  const float* ck = (const float*)d_in[4];
  const float* mn = (const float*)d_in[5];
  float* out = (float*)d_out;

  unsigned short* wsKV = (unsigned short*)d_ws;                            // 4 MiB states
  unsigned short* wsVT = (unsigned short*)((char*)d_ws + 4u * 1024u * 1024u); // 4 MiB v^T

  k_chunk_sums<<<dim3(NC, H), dim3(512), 0, stream>>>(k, v, q, ck, wsKV, wsVT);
  k_scan<<<dim3(32, H), dim3(64), 0, stream>>>((unsigned*)d_ws);
  k_chunk_out<<<dim3(NC, H), dim3(512), 0, stream>>>(q, k, cq, ck, mn, wsKV, wsVT, out);
}